// Round 12
// baseline (295.144 us; speedup 1.0000x reference)
//
#include <hip/hip_runtime.h>

// DIM=256 H=8 HD=32 W=64 N=8192 nw=128
// xyz: T=40, off=20, hi=39, R=120 (pad 128) ; rgb: T=32, off=16, hi=31, R=96
// table element ((c*T+t)*8+h)*32+d == r*256 + h*32 + d, r=c*T+t

typedef __attribute__((ext_vector_type(8))) short short8;
typedef __attribute__((ext_vector_type(4))) float f32x4;

__device__ __forceinline__ unsigned short f2bf(float f) {
    union { float f; unsigned int u; } v; v.f = f;
    unsigned int r = v.u + 0x7FFFu + ((v.u >> 16) & 1u);
    return (unsigned short)(r >> 16);
}

// ---------------------------------------------------------------------------
// QKV GEMM (bf16 MFMA), fp32 inputs cast inline during staging.
// ---------------------------------------------------------------------------
__global__ __launch_bounds__(256) void k_qkv(
    const float* __restrict__ A, const float* __restrict__ B,
    const float* __restrict__ bias,
    ushort* __restrict__ qb, ushort* __restrict__ kb, ushort* __restrict__ vb)
{
    __shared__ __align__(16) ushort a_s[128 * 72];
    __shared__ __align__(16) ushort b_s[64 * 72];
    const int tid = threadIdx.x;
    const int m0 = blockIdx.y * 128;
    const int n0 = blockIdx.x * 64;
    const int w = tid >> 6, wm = w >> 1, wn = w & 1;
    const int l4 = tid & 15, quad = (tid >> 4) & 3;
    f32x4 acc[4][2];
#pragma unroll
    for (int mt = 0; mt < 4; ++mt)
#pragma unroll
        for (int nt = 0; nt < 2; ++nt) acc[mt][nt] = (f32x4){0.f, 0.f, 0.f, 0.f};

    for (int k0 = 0; k0 < 256; k0 += 64) {
#pragma unroll
        for (int l = 0; l < 4; ++l) {
            int e = tid + l * 256;
            int row = e >> 3, kq = e & 7;
            const float* ap = A + (size_t)(m0 + row) * 256 + k0 + kq * 8;
            float4 v0 = *(const float4*)ap, v1 = *(const float4*)(ap + 4);
            union { ushort u[8]; uint4 v; } pk;
            pk.u[0] = f2bf(v0.x); pk.u[1] = f2bf(v0.y); pk.u[2] = f2bf(v0.z); pk.u[3] = f2bf(v0.w);
            pk.u[4] = f2bf(v1.x); pk.u[5] = f2bf(v1.y); pk.u[6] = f2bf(v1.z); pk.u[7] = f2bf(v1.w);
            *(uint4*)&a_s[row * 72 + kq * 8] = pk.v;
        }
#pragma unroll
        for (int l = 0; l < 2; ++l) {
            int e = tid + l * 256;
            int row = e >> 3, kq = e & 7;
            const float* bp = B + (size_t)(n0 + row) * 256 + k0 + kq * 8;
            float4 v0 = *(const float4*)bp, v1 = *(const float4*)(bp + 4);
            union { ushort u[8]; uint4 v; } pk;
            pk.u[0] = f2bf(v0.x); pk.u[1] = f2bf(v0.y); pk.u[2] = f2bf(v0.z); pk.u[3] = f2bf(v0.w);
            pk.u[4] = f2bf(v1.x); pk.u[5] = f2bf(v1.y); pk.u[6] = f2bf(v1.z); pk.u[7] = f2bf(v1.w);
            *(uint4*)&b_s[row * 72 + kq * 8] = pk.v;
        }
        __syncthreads();
#pragma unroll
        for (int kh = 0; kh < 2; ++kh) {
            short8 bf0 = *(const short8*)&b_s[(wn * 32 + l4) * 72 + kh * 32 + quad * 8];
            short8 bf1 = *(const short8*)&b_s[(wn * 32 + 16 + l4) * 72 + kh * 32 + quad * 8];
#pragma unroll
            for (int mt = 0; mt < 4; ++mt) {
                short8 af = *(const short8*)&a_s[(wm * 64 + mt * 16 + l4) * 72 + kh * 32 + quad * 8];
                acc[mt][0] = __builtin_amdgcn_mfma_f32_16x16x32_bf16(af, bf0, acc[mt][0], 0, 0, 0);
                acc[mt][1] = __builtin_amdgcn_mfma_f32_16x16x32_bf16(af, bf1, acc[mt][1], 0, 0, 0);
            }
        }
        __syncthreads();
    }
#pragma unroll
    for (int nt = 0; nt < 2; ++nt) {
        int c = n0 + wn * 32 + nt * 16 + l4;
        float bv = bias[c];
        int s = c >> 8, rem = c & 255, h = rem >> 5, d = rem & 31;
        ushort* dst = (s == 0) ? qb : ((s == 1) ? kb : vb);
        float mul = (s == 0) ? 0.17677669529663687f : 1.0f;
#pragma unroll
        for (int mt = 0; mt < 4; ++mt) {
            int mbase = m0 + wm * 64 + mt * 16 + quad * 4;
#pragma unroll
            for (int reg = 0; reg < 4; ++reg) {
                int m = mbase + reg;
                int nw = m >> 6, ii = m & 63;
                dst[((size_t)((nw * 8 + h) * 64 + ii)) * 32 + d] = f2bf((acc[mt][nt][reg] + bv) * mul);
            }
        }
    }
}

// ---------------------------------------------------------------------------
// MFMA attention per (window, head). Config-A structure (round-10 bench,
// 167 µs) + packed idx REGISTERS computed once (removes ~360 scalar cwf LDS
// reads/thread — the kernel is LDS-issue-throughput-bound: occupancy 1 vs 2
// waves/SIMD changed dur by only 4% across rounds 7-11).
//   idxX[4][4]: x0|x1<<8|x2<<16.  idxRp[2][4]: two 15-bit rgb triples
//   (r0|r1<<5|r2<<10) per int.  Constant-indexed, never address-taken.
// __launch_bounds__(256,2): total unified regs <= 256 -> 2 waves/SIMD without
// scratch spill (R4-6: min=3 pins arch at 84 and spills; unbounded (R9):
// 172 arch -> >256 total -> 1 wave). Spill tripwire: WRITE_SIZE >> 4.1 MB.
// LDS: dbuf fp32 64x122 (31,232) + U (22,528) + cwf (1,536) = 55,296 B.
// ---------------------------------------------------------------------------
#define DBS 122

__global__ __launch_bounds__(256, 2) void k_attn(
    const ushort* __restrict__ qb, const ushort* __restrict__ kb, const ushort* __restrict__ vb,
    const float* __restrict__ nco,
    const float* __restrict__ qxt, const float* __restrict__ kxt, const float* __restrict__ vxt,
    const float* __restrict__ qrt, const float* __restrict__ krt, const float* __restrict__ vrt,
    ushort* __restrict__ aout)
{
    __shared__ __align__(16) float dbuf[64 * DBS];
    __shared__ __align__(16) ushort U[11264];
    __shared__ __align__(16) float cwf[64 * 6];   // used only for idx precompute
    // Phase A overlays:
    ushort* q_s  = U;              // [64][40]
    ushort* k_s  = U + 2560;       // [64][40]
    ushort* tbl  = U + 5120;       // [128][40]
    // Phase B overlays:
    ushort* attn_s = U;            // [64][72]
    ushort* v_t    = U + 4608;     // [32][72]
    ushort* vtbl   = U + 6912;     // [32][136]

    const int tid = threadIdx.x;
    const int n = blockIdx.x >> 3;
    const int h = blockIdx.x & 7;
    const int w = tid >> 6;
    const int l4 = tid & 15;
    const int quad = (tid >> 4) & 3;

    const size_t base = (size_t)((n * 8 + h) * 64) * 32;

    // ---- stage q, k, coords ----
    {
        int row = tid >> 2, part = tid & 3;
        *(uint4*)&q_s[row * 40 + part * 8] = *(const uint4*)(qb + base + tid * 8);
        *(uint4*)&k_s[row * 40 + part * 8] = *(const uint4*)(kb + base + tid * 8);
    }
    if (tid < 64) {
        const float* cp = nco + (size_t)(n * 64 + tid) * 6;
        cwf[tid * 6 + 0] = cp[0] * 4.f; cwf[tid * 6 + 1] = cp[1] * 4.f;
        cwf[tid * 6 + 2] = cp[2] * 4.f; cwf[tid * 6 + 3] = cp[3] * 8.f;
        cwf[tid * 6 + 4] = cp[4] * 8.f; cwf[tid * 6 + 5] = cp[5] * 8.f;
    }

    auto stageTbl = [&](const float* tbg, int R, int Rpad) {
        for (int e = tid; e < R * 4; e += 256) {
            int r = e >> 2, part = e & 3;
            const float* src = tbg + (size_t)r * 256 + part * 8;
            float4 f0 = *(const float4*)src, f1 = *(const float4*)(src + 4);
            union { ushort u[8]; uint4 v; } pk;
            pk.u[0] = f2bf(f0.x); pk.u[1] = f2bf(f0.y); pk.u[2] = f2bf(f0.z); pk.u[3] = f2bf(f0.w);
            pk.u[4] = f2bf(f1.x); pk.u[5] = f2bf(f1.y); pk.u[6] = f2bf(f1.z); pk.u[7] = f2bf(f1.w);
            *(uint4*)&tbl[r * 40 + part * 8] = pk.v;
        }
        for (int e = tid; e < (Rpad - R) * 40; e += 256) tbl[R * 40 + e] = 0;
    };
    auto stageVtbl = [&](const float* tbg, int R) {
        for (int e = tid; e < R * 4; e += 256) {
            int r = e >> 2, part = e & 3;
            const float* src = tbg + (size_t)r * 256 + part * 8;
            float4 f0 = *(const float4*)src, f1 = *(const float4*)(src + 4);
            int d0 = part * 8;
            vtbl[(d0 + 0) * 136 + r] = f2bf(f0.x);
            vtbl[(d0 + 1) * 136 + r] = f2bf(f0.y);
            vtbl[(d0 + 2) * 136 + r] = f2bf(f0.z);
            vtbl[(d0 + 3) * 136 + r] = f2bf(f0.w);
            vtbl[(d0 + 4) * 136 + r] = f2bf(f1.x);
            vtbl[(d0 + 5) * 136 + r] = f2bf(f1.y);
            vtbl[(d0 + 6) * 136 + r] = f2bf(f1.z);
            vtbl[(d0 + 7) * 136 + r] = f2bf(f1.w);
        }
        int span = 128 - R;
        for (int e = tid; e < 32 * span; e += 256) {
            int d = e / span, rr = e - d * span;
            vtbl[d * 136 + R + rr] = 0;
        }
    };
    auto stageVt = [&]() {
        int j = tid >> 2, d0 = (tid & 3) * 8;
        uint4 pk = *(const uint4*)(vb + base + tid * 8);
        const ushort* u = (const ushort*)&pk;
#pragma unroll
        for (int ii = 0; ii < 8; ++ii) v_t[(d0 + ii) * 72 + j] = u[ii];
    };

    auto tgemm = [&](const ushort* a_s, int NT, int maxc) {
        short8 af = *(const short8*)&a_s[(w * 16 + l4) * 40 + quad * 8];
        for (int tt = 0; tt < NT; ++tt) {
            short8 bf = *(const short8*)&tbl[(tt * 16 + l4) * 40 + quad * 8];
            f32x4 a = {0.f, 0.f, 0.f, 0.f};
            a = __builtin_amdgcn_mfma_f32_16x16x32_bf16(af, bf, a, 0, 0, 0);
            int col = tt * 16 + l4;
            int rb = w * 16 + quad * 4;
            if (col < maxc) {
                dbuf[(rb + 0) * DBS + col] = a[0];
                dbuf[(rb + 1) * DBS + col] = a[1];
                dbuf[(rb + 2) * DBS + col] = a[2];
                dbuf[(rb + 3) * DBS + col] = a[3];
            }
        }
    };

    stageTbl(kxt + h * 32, 120, 128);
    __syncthreads();

    // ---- precompute packed gather/scatter indices ONCE into registers ----
    int idxX[4][4], idxRp[2][4];
#pragma unroll
    for (int tt = 0; tt < 4; ++tt) {
        int j = tt * 16 + l4;
        float cj0 = cwf[j * 6 + 0], cj1 = cwf[j * 6 + 1], cj2 = cwf[j * 6 + 2];
        float cj3 = cwf[j * 6 + 3], cj4 = cwf[j * 6 + 4], cj5 = cwf[j * 6 + 5];
#pragma unroll
        for (int reg = 0; reg < 4; ++reg) {
            int i = w * 16 + quad * 4 + reg;
            int x0 = min(max((int)floorf(cwf[i * 6 + 0] - cj0) + 20, 0), 39);
            int x1 = min(max((int)floorf(cwf[i * 6 + 1] - cj1) + 20, 0), 39);
            int x2 = min(max((int)floorf(cwf[i * 6 + 2] - cj2) + 20, 0), 39);
            idxX[tt][reg] = x0 | (x1 << 8) | (x2 << 16);
            int r0 = min(max((int)floorf(cwf[i * 6 + 3] - cj3) + 16, 0), 31);
            int r1 = min(max((int)floorf(cwf[i * 6 + 4] - cj4) + 16, 0), 31);
            int r2 = min(max((int)floorf(cwf[i * 6 + 5] - cj5) + 16, 0), 31);
            int tr = r0 | (r1 << 5) | (r2 << 10);
            if (tt < 2) idxRp[tt][reg] = tr;
            else        idxRp[tt - 2][reg] |= tr << 15;
        }
    }

    float lg[4][4];   // [tt][reg]: row i = w*16+quad*4+reg, col j = tt*16+l4

    auto gatherX = [&](bool useJ) {
#pragma unroll
        for (int tt = 0; tt < 4; ++tt) {
#pragma unroll
            for (int reg = 0; reg < 4; ++reg) {
                int p = idxX[tt][reg];
                int b = (useJ ? (tt * 16 + l4) : (w * 16 + quad * 4 + reg)) * DBS;
                lg[tt][reg] += dbuf[b + (p & 255)] + dbuf[b + 40 + ((p >> 8) & 255)]
                             + dbuf[b + 80 + (p >> 16)];
            }
        }
    };
    auto gatherR = [&](bool useJ) {
#pragma unroll
        for (int tt = 0; tt < 4; ++tt) {
#pragma unroll
            for (int reg = 0; reg < 4; ++reg) {
                int p = (idxRp[tt & 1][reg] >> ((tt >> 1) * 15)) & 0x7FFF;
                int b = (useJ ? (tt * 16 + l4) : (w * 16 + quad * 4 + reg)) * DBS;
                lg[tt][reg] += dbuf[b + (p & 31)] + dbuf[b + 32 + ((p >> 5) & 31)]
                             + dbuf[b + 64 + ((p >> 10) & 31)];
            }
        }
    };
    auto scatterX = [&]() {
#pragma unroll
        for (int reg = 0; reg < 4; ++reg) {
            float* bi = &dbuf[(w * 16 + quad * 4 + reg) * DBS];
#pragma unroll
            for (int tt = 0; tt < 4; ++tt) {
                int p = idxX[tt][reg];
                float a = lg[tt][reg];
                atomicAdd(bi + (p & 255), a);
                atomicAdd(bi + 40 + ((p >> 8) & 255), a);
                atomicAdd(bi + 80 + (p >> 16), a);
            }
        }
    };
    auto scatterR = [&]() {
#pragma unroll
        for (int reg = 0; reg < 4; ++reg) {
            float* bi = &dbuf[(w * 16 + quad * 4 + reg) * DBS];
#pragma unroll
            for (int tt = 0; tt < 4; ++tt) {
                int p = (idxRp[tt & 1][reg] >> ((tt >> 1) * 15)) & 0x7FFF;
                float a = lg[tt][reg];
                atomicAdd(bi + (p & 31), a);
                atomicAdd(bi + 32 + ((p >> 5) & 31), a);
                atomicAdd(bi + 64 + ((p >> 10) & 31), a);
            }
        }
    };
    auto zeroBins = [&]() {
        float4 z = {0.f, 0.f, 0.f, 0.f};
        for (int e = tid * 4; e < 64 * DBS; e += 1024) *(float4*)&dbuf[e] = z;
    };

    // ---- QK logits + dk_xyz ----
    {
        short8 aq = *(const short8*)&q_s[(w * 16 + l4) * 40 + quad * 8];
#pragma unroll
        for (int tt = 0; tt < 4; ++tt) {
            short8 bk = *(const short8*)&k_s[(tt * 16 + l4) * 40 + quad * 8];
            f32x4 r = {0.f, 0.f, 0.f, 0.f};
            r = __builtin_amdgcn_mfma_f32_16x16x32_bf16(aq, bk, r, 0, 0, 0);
            lg[tt][0] = r[0]; lg[tt][1] = r[1]; lg[tt][2] = r[2]; lg[tt][3] = r[3];
        }
    }
    tgemm(k_s, 8, 120);                  // dk_xyz
    __syncthreads();
    gatherX(true);                       // bias_k xyz
    stageTbl(krt + h * 32, 96, 96);
    __syncthreads();
    tgemm(k_s, 6, 96);                   // dk_rgb
    __syncthreads();
    gatherR(true);                       // bias_k rgb
    stageTbl(qxt + h * 32, 120, 128);
    __syncthreads();
    tgemm(q_s, 8, 120);                  // dq_xyz
    __syncthreads();
    gatherX(false);                      // bias_q xyz
    stageTbl(qrt + h * 32, 96, 96);
    __syncthreads();
    tgemm(q_s, 6, 96);                   // dq_rgb
    __syncthreads();
    gatherR(false);                      // bias_q rgb
    stageVtbl(vxt + h * 32, 120);        // tbl region dead now
    stageVt();                           // k_s tail dead now
    __syncthreads();

    // ---- softmax ----
#pragma unroll
    for (int reg = 0; reg < 4; ++reg) {
        float m = fmaxf(fmaxf(lg[0][reg], lg[1][reg]), fmaxf(lg[2][reg], lg[3][reg]));
        m = fmaxf(m, __shfl_xor(m, 1));
        m = fmaxf(m, __shfl_xor(m, 2));
        m = fmaxf(m, __shfl_xor(m, 4));
        m = fmaxf(m, __shfl_xor(m, 8));
        float s = 0.f;
#pragma unroll
        for (int tt = 0; tt < 4; ++tt) { lg[tt][reg] = __expf(lg[tt][reg] - m); s += lg[tt][reg]; }
        s += __shfl_xor(s, 1); s += __shfl_xor(s, 2);
        s += __shfl_xor(s, 4); s += __shfl_xor(s, 8);
        float inv = 1.f / s;
#pragma unroll
        for (int tt = 0; tt < 4; ++tt) lg[tt][reg] *= inv;
    }
#pragma unroll
    for (int tt = 0; tt < 4; ++tt)
#pragma unroll
        for (int reg = 0; reg < 4; ++reg)
            attn_s[(w * 16 + quad * 4 + reg) * 72 + tt * 16 + l4] = f2bf(lg[tt][reg]);
    zeroBins();
    __syncthreads();

    // ---- scatter xyz bins + AV ----
    scatterX();
    f32x4 acc0 = {0.f, 0.f, 0.f, 0.f}, acc1 = {0.f, 0.f, 0.f, 0.f};
#pragma unroll
    for (int s = 0; s < 2; ++s) {
        short8 af = *(const short8*)&attn_s[(w * 16 + l4) * 72 + s * 32 + quad * 8];
        short8 b0 = *(const short8*)&v_t[l4 * 72 + s * 32 + quad * 8];
        short8 b1 = *(const short8*)&v_t[(16 + l4) * 72 + s * 32 + quad * 8];
        acc0 = __builtin_amdgcn_mfma_f32_16x16x32_bf16(af, b0, acc0, 0, 0, 0);
        acc1 = __builtin_amdgcn_mfma_f32_16x16x32_bf16(af, b1, acc1, 0, 0, 0);
    }
    __syncthreads();

    auto atgemm = [&](int Rlim) {
#pragma unroll
        for (int s = 0; s < 4; ++s) {
            int koff = s * 32 + quad * 8;
            short8 af = {0, 0, 0, 0, 0, 0, 0, 0};
            if (koff < Rlim) {
                const float* ap = &dbuf[(w * 16 + l4) * DBS + koff];
#pragma unroll
                for (int ii = 0; ii < 8; ++ii) af[ii] = (short)f2bf(ap[ii]);
            }
            short8 b0 = *(const short8*)&vtbl[l4 * 136 + koff];
            short8 b1 = *(const short8*)&vtbl[(16 + l4) * 136 + koff];
            acc0 = __builtin_amdgcn_mfma_f32_16x16x32_bf16(af, b0, acc0, 0, 0, 0);
            acc1 = __builtin_amdgcn_mfma_f32_16x16x32_bf16(af, b1, acc1, 0, 0, 0);
        }
    };
    atgemm(120);                         // value-bias xyz
    __syncthreads();
    zeroBins();
    stageVtbl(vrt + h * 32, 96);
    __syncthreads();
    scatterR();
    __syncthreads();
    atgemm(96);                          // value-bias rgb

    // ---- epilogue: bf16 ao[i][h*32+d] ----
    {
        ushort* op = aout + (size_t)(n * 64 + w * 16 + quad * 4) * 256 + h * 32;
#pragma unroll
        for (int reg = 0; reg < 4; ++reg) {
            op[reg * 256 + l4] = f2bf(acc0[reg]);
            op[reg * 256 + 16 + l4] = f2bf(acc1[reg]);
        }
    }
}

// ---------------------------------------------------------------------------
// Proj GEMM (bf16 MFMA): out = ao(bf16) @ proj_w(fp32, cast inline)^T + pb
// ---------------------------------------------------------------------------
__global__ __launch_bounds__(256) void k_proj(
    const ushort* __restrict__ A, const float* __restrict__ B,
    const float* __restrict__ bias, float* __restrict__ out)
{
    __shared__ __align__(16) ushort a_s[128 * 72];
    __shared__ __align__(16) ushort b_s[64 * 72];
    const int tid = threadIdx.x;
    const int m0 = blockIdx.y * 128;
    const int n0 = blockIdx.x * 64;
    const int w = tid >> 6, wm = w >> 1, wn = w & 1;
    const int l4 = tid & 15, quad = (tid >> 4) & 3;
    f32x4 acc[4][2];
#pragma unroll
    for (int mt = 0; mt < 4; ++mt)
#pragma unroll
        for (int nt = 0; nt < 2; ++nt) acc[mt][nt] = (f32x4){0.f, 0.f, 0.f, 0.f};

    for (int k0 = 0; k0 < 256; k0 += 64) {
#pragma unroll
        for (int l = 0; l < 4; ++l) {
            int e = tid + l * 256;
            int row = e >> 3, kq = e & 7;
            *(uint4*)&a_s[row * 72 + kq * 8] =
                *(const uint4*)(A + (size_t)(m0 + row) * 256 + k0 + kq * 8);
        }
#pragma unroll
        for (int l = 0; l < 2; ++l) {
            int e = tid + l * 256;
            int row = e >> 3, kq = e & 7;
            const float* bp = B + (size_t)(n0 + row) * 256 + k0 + kq * 8;
            float4 v0 = *(const float4*)bp, v1 = *(const float4*)(bp + 4);
            union { ushort u[8]; uint4 v; } pk;
            pk.u[0] = f2bf(v0.x); pk.u[1] = f2bf(v0.y); pk.u[2] = f2bf(v0.z); pk.u[3] = f2bf(v0.w);
            pk.u[4] = f2bf(v1.x); pk.u[5] = f2bf(v1.y); pk.u[6] = f2bf(v1.z); pk.u[7] = f2bf(v1.w);
            *(uint4*)&b_s[row * 72 + kq * 8] = pk.v;
        }
        __syncthreads();
#pragma unroll
        for (int kh = 0; kh < 2; ++kh) {
            short8 bf0 = *(const short8*)&b_s[(wn * 32 + l4) * 72 + kh * 32 + quad * 8];
            short8 bf1 = *(const short8*)&b_s[(wn * 32 + 16 + l4) * 72 + kh * 32 + quad * 8];
#pragma unroll
            for (int mt = 0; mt < 4; ++mt) {
                short8 af = *(const short8*)&a_s[(wm * 64 + mt * 16 + l4) * 72 + kh * 32 + quad * 8];
                acc[mt][0] = __builtin_amdgcn_mfma_f32_16x16x32_bf16(af, bf0, acc[mt][0], 0, 0, 0);
                acc[mt][1] = __builtin_amdgcn_mfma_f32_16x16x32_bf16(af, bf1, acc[mt][1], 0, 0, 0);
            }
        }
        __syncthreads();
    }
#pragma unroll
    for (int nt = 0; nt < 2; ++nt) {
        int c = n0 + wn * 32 + nt * 16 + l4;
        float bv = bias[c];
#pragma unroll
        for (int mt = 0; mt < 4; ++mt) {
            int mbase = m0 + wm * 64 + mt * 16 + quad * 4;
#pragma unroll
            for (int reg = 0; reg < 4; ++reg)
                out[(size_t)(mbase + reg) * 256 + c] = acc[mt][nt][reg] + bv;
        }
    }
}

extern "C" void kernel_launch(void* const* d_in, const int* in_sizes, int n_in,
                              void* d_out, int out_size, void* d_ws, size_t ws_size,
                              hipStream_t stream)
{
    const float* feats = (const float*)d_in[0];
    const float* nco   = (const float*)d_in[1];
    const float* qkvw  = (const float*)d_in[2];
    const float* qkvb  = (const float*)d_in[3];
    const float* qxt   = (const float*)d_in[4];
    const float* kxt   = (const float*)d_in[5];
    const float* vxt   = (const float*)d_in[6];
    const float* qrt   = (const float*)d_in[7];
    const float* krt   = (const float*)d_in[8];
    const float* vrt   = (const float*)d_in[9];
    const float* pw    = (const float*)d_in[10];
    const float* pb    = (const float*)d_in[11];
    float* out = (float*)d_out;

    ushort* qb  = (ushort*)d_ws;                       // [128][8][64][32] bf16
    ushort* kb  = qb + (size_t)2097152;
    ushort* vb  = kb + (size_t)2097152;
    ushort* aob = vb + (size_t)2097152;                // [8192][256] bf16

    k_qkv<<<dim3(12, 64), 256, 0, stream>>>(feats, qkvw, qkvb, qb, kb, vb);
    k_attn<<<dim3(1024), 256, 0, stream>>>(qb, kb, vb, nco, qxt, kxt, vxt, qrt, krt, vrt, aob);
    k_proj<<<dim3(4, 64), 256, 0, stream>>>(aob, pw, pb, out);
}

// Round 13
// 282.320 us; speedup vs baseline: 1.0454x; 1.0454x over previous
//
#include <hip/hip_runtime.h>

// DIM=256 H=8 HD=32 W=64 N=8192 nw=128
// xyz: T=40, off=20, hi=39, R=120 ; rgb: T=32, off=16, hi=31, R=96
// table element ((c*T+t)*8+h)*32+d == r*256 + h*32 + d, r=c*T+t
// dk/dq global: [n*8+h][64 rows][224] bf16 (xyz cols 0..119, pad, rgb 128..223)

typedef __attribute__((ext_vector_type(8))) short short8;
typedef __attribute__((ext_vector_type(4))) float f32x4;

__device__ __forceinline__ unsigned short f2bf(float f) {
    union { float f; unsigned int u; } v; v.f = f;
    unsigned int r = v.u + 0x7FFFu + ((v.u >> 16) & 1u);
    return (unsigned short)(r >> 16);
}
__device__ __forceinline__ float bf2f(ushort u) {
    union { unsigned int u; float f; } v; v.u = ((unsigned int)u) << 16;
    return v.f;
}

// ---------------------------------------------------------------------------
// QKV GEMM (bf16 MFMA), fp32 inputs cast inline during staging.
// ---------------------------------------------------------------------------
__global__ __launch_bounds__(256) void k_qkv(
    const float* __restrict__ A, const float* __restrict__ B,
    const float* __restrict__ bias,
    ushort* __restrict__ qb, ushort* __restrict__ kb, ushort* __restrict__ vb)
{
    __shared__ __align__(16) ushort a_s[128 * 72];
    __shared__ __align__(16) ushort b_s[64 * 72];
    const int tid = threadIdx.x;
    const int m0 = blockIdx.y * 128;
    const int n0 = blockIdx.x * 64;
    const int w = tid >> 6, wm = w >> 1, wn = w & 1;
    const int l4 = tid & 15, quad = (tid >> 4) & 3;
    f32x4 acc[4][2];
#pragma unroll
    for (int mt = 0; mt < 4; ++mt)
#pragma unroll
        for (int nt = 0; nt < 2; ++nt) acc[mt][nt] = (f32x4){0.f, 0.f, 0.f, 0.f};

    for (int k0 = 0; k0 < 256; k0 += 64) {
#pragma unroll
        for (int l = 0; l < 4; ++l) {
            int e = tid + l * 256;
            int row = e >> 3, kq = e & 7;
            const float* ap = A + (size_t)(m0 + row) * 256 + k0 + kq * 8;
            float4 v0 = *(const float4*)ap, v1 = *(const float4*)(ap + 4);
            union { ushort u[8]; uint4 v; } pk;
            pk.u[0] = f2bf(v0.x); pk.u[1] = f2bf(v0.y); pk.u[2] = f2bf(v0.z); pk.u[3] = f2bf(v0.w);
            pk.u[4] = f2bf(v1.x); pk.u[5] = f2bf(v1.y); pk.u[6] = f2bf(v1.z); pk.u[7] = f2bf(v1.w);
            *(uint4*)&a_s[row * 72 + kq * 8] = pk.v;
        }
#pragma unroll
        for (int l = 0; l < 2; ++l) {
            int e = tid + l * 256;
            int row = e >> 3, kq = e & 7;
            const float* bp = B + (size_t)(n0 + row) * 256 + k0 + kq * 8;
            float4 v0 = *(const float4*)bp, v1 = *(const float4*)(bp + 4);
            union { ushort u[8]; uint4 v; } pk;
            pk.u[0] = f2bf(v0.x); pk.u[1] = f2bf(v0.y); pk.u[2] = f2bf(v0.z); pk.u[3] = f2bf(v0.w);
            pk.u[4] = f2bf(v1.x); pk.u[5] = f2bf(v1.y); pk.u[6] = f2bf(v1.z); pk.u[7] = f2bf(v1.w);
            *(uint4*)&b_s[row * 72 + kq * 8] = pk.v;
        }
        __syncthreads();
#pragma unroll
        for (int kh = 0; kh < 2; ++kh) {
            short8 bf0 = *(const short8*)&b_s[(wn * 32 + l4) * 72 + kh * 32 + quad * 8];
            short8 bf1 = *(const short8*)&b_s[(wn * 32 + 16 + l4) * 72 + kh * 32 + quad * 8];
#pragma unroll
            for (int mt = 0; mt < 4; ++mt) {
                short8 af = *(const short8*)&a_s[(wm * 64 + mt * 16 + l4) * 72 + kh * 32 + quad * 8];
                acc[mt][0] = __builtin_amdgcn_mfma_f32_16x16x32_bf16(af, bf0, acc[mt][0], 0, 0, 0);
                acc[mt][1] = __builtin_amdgcn_mfma_f32_16x16x32_bf16(af, bf1, acc[mt][1], 0, 0, 0);
            }
        }
        __syncthreads();
    }
#pragma unroll
    for (int nt = 0; nt < 2; ++nt) {
        int c = n0 + wn * 32 + nt * 16 + l4;
        float bv = bias[c];
        int s = c >> 8, rem = c & 255, h = rem >> 5, d = rem & 31;
        ushort* dst = (s == 0) ? qb : ((s == 1) ? kb : vb);
        float mul = (s == 0) ? 0.17677669529663687f : 1.0f;
#pragma unroll
        for (int mt = 0; mt < 4; ++mt) {
            int mbase = m0 + wm * 64 + mt * 16 + quad * 4;
#pragma unroll
            for (int reg = 0; reg < 4; ++reg) {
                int m = mbase + reg;
                int nw = m >> 6, ii = m & 63;
                dst[((size_t)((nw * 8 + h) * 64 + ii)) * 32 + d] = f2bf((acc[mt][nt][reg] + bv) * mul);
            }
        }
    }
}

// ---------------------------------------------------------------------------
// k_dt: batched table GEMM. dk[blk][j][r] = k[blk,j,:]·tbl_k[r,:],
// dq likewise with q tables. blk = n*8+h; r: xyz rows 0..119 (120..127 zero),
// rgb at 128..223. Moves 4 stageTbl + 4 tgemm phases out of k_attn.
// ---------------------------------------------------------------------------
__global__ __launch_bounds__(256) void k_dt(
    const ushort* __restrict__ qb, const ushort* __restrict__ kb,
    const float* __restrict__ qxt, const float* __restrict__ kxt,
    const float* __restrict__ qrt, const float* __restrict__ krt,
    ushort* __restrict__ dkg, ushort* __restrict__ dqg)
{
    __shared__ __align__(16) ushort q_s[64 * 40];
    __shared__ __align__(16) ushort k_s[64 * 40];
    __shared__ __align__(16) ushort tbl[224 * 40];
    const int tid = threadIdx.x;
    const int h = blockIdx.x & 7;
    const int w = tid >> 6, l4 = tid & 15, quad = (tid >> 4) & 3;
    const size_t base = (size_t)blockIdx.x * 64 * 32;

    {
        int row = tid >> 2, part = tid & 3;
        *(uint4*)&q_s[row * 40 + part * 8] = *(const uint4*)(qb + base + tid * 8);
        *(uint4*)&k_s[row * 40 + part * 8] = *(const uint4*)(kb + base + tid * 8);
    }
    auto stagePair = [&](const float* tx, const float* tr) {
        for (int e = tid; e < 480; e += 256) {
            int r = e >> 2, part = e & 3;
            const float* src = tx + (size_t)r * 256 + part * 8;
            float4 f0 = *(const float4*)src, f1 = *(const float4*)(src + 4);
            union { ushort u[8]; uint4 v; } pk;
            pk.u[0] = f2bf(f0.x); pk.u[1] = f2bf(f0.y); pk.u[2] = f2bf(f0.z); pk.u[3] = f2bf(f0.w);
            pk.u[4] = f2bf(f1.x); pk.u[5] = f2bf(f1.y); pk.u[6] = f2bf(f1.z); pk.u[7] = f2bf(f1.w);
            *(uint4*)&tbl[r * 40 + part * 8] = pk.v;
        }
        for (int e = tid; e < 320; e += 256) tbl[4800 + e] = 0;   // rows 120..127
        for (int e = tid; e < 384; e += 256) {
            int r = e >> 2, part = e & 3;
            const float* src = tr + (size_t)r * 256 + part * 8;
            float4 f0 = *(const float4*)src, f1 = *(const float4*)(src + 4);
            union { ushort u[8]; uint4 v; } pk;
            pk.u[0] = f2bf(f0.x); pk.u[1] = f2bf(f0.y); pk.u[2] = f2bf(f0.z); pk.u[3] = f2bf(f0.w);
            pk.u[4] = f2bf(f1.x); pk.u[5] = f2bf(f1.y); pk.u[6] = f2bf(f1.z); pk.u[7] = f2bf(f1.w);
            *(uint4*)&tbl[(128 + r) * 40 + part * 8] = pk.v;
        }
    };
    auto runGemm = [&](const ushort* x_s, ushort* outg) {
        short8 af = *(const short8*)&x_s[(w * 16 + l4) * 40 + quad * 8];
        size_t rowg = (size_t)blockIdx.x * 64 + w * 16 + quad * 4;
#pragma unroll
        for (int tt = 0; tt < 14; ++tt) {
            short8 bf = *(const short8*)&tbl[(tt * 16 + l4) * 40 + quad * 8];
            f32x4 a = {0.f, 0.f, 0.f, 0.f};
            a = __builtin_amdgcn_mfma_f32_16x16x32_bf16(af, bf, a, 0, 0, 0);
            int col = tt * 16 + l4;
#pragma unroll
            for (int reg = 0; reg < 4; ++reg)
                outg[(rowg + reg) * 224 + col] = f2bf(a[reg]);
        }
    };
    stagePair(kxt + h * 32, krt + h * 32);
    __syncthreads();
    runGemm(k_s, dkg);
    __syncthreads();
    stagePair(qxt + h * 32, qrt + h * 32);
    __syncthreads();
    runGemm(q_s, dqg);
}

// ---------------------------------------------------------------------------
// k_attn (split path): 10 segments (was 15). dk/dq staged from global.
// LDS el-layout (L[28928] ushort, 57,856 B):
//   q_s@0[64][40], k_s@2560, dkq@5120 (stride 232, 14,848 el of 15,616 region)
//   vtbl@20736[32][136], v_t@25088[32][72], cwf f32 @27392 (1536 el)
//   overlays: attn_s@0[64][72]; bins f32[64][122] over dkq region.
// Register discipline = R10 proven (recompute idx from cwf, (256,2), no idx
// arrays). Spill tripwire: WRITE_SIZE >> 4.1 MB.
// ---------------------------------------------------------------------------
__global__ __launch_bounds__(256, 2) void k_attn_split(
    const ushort* __restrict__ qb, const ushort* __restrict__ kb, const ushort* __restrict__ vb,
    const float* __restrict__ nco,
    const ushort* __restrict__ dkg, const ushort* __restrict__ dqg,
    const float* __restrict__ vxt, const float* __restrict__ vrt,
    ushort* __restrict__ aout)
{
    __shared__ __align__(16) ushort L[28928];
    ushort* q_s   = L;
    ushort* k_s   = L + 2560;
    ushort* dkq   = L + 5120;              // stride 232
    ushort* vtbl  = L + 20736;             // [32][136]
    ushort* v_t   = L + 25088;             // [32][72]
    float*  cwf   = (float*)(L + 27392);   // [64][6]
    ushort* attn_s = L;                    // [64][72]
    float*  bins   = (float*)(L + 5120);   // [64][122]

    const int tid = threadIdx.x;
    const int n = blockIdx.x >> 3;
    const int h = blockIdx.x & 7;
    const int w = tid >> 6;
    const int l4 = tid & 15;
    const int quad = (tid >> 4) & 3;

    const size_t base = (size_t)blockIdx.x * 64 * 32;
    const size_t dbase = (size_t)blockIdx.x * 64 * 224;

    auto stageD = [&](const ushort* src) {
        for (int e = tid; e < 1792; e += 256) {
            int row = e / 28, part = e - row * 28;
            *(uint4*)&dkq[row * 232 + part * 8] =
                *(const uint4*)(src + dbase + (size_t)row * 224 + part * 8);
        }
    };
    auto stageVtbl = [&](const float* tbg, int R) {
        for (int e = tid; e < R * 4; e += 256) {
            int r = e >> 2, part = e & 3;
            const float* src = tbg + (size_t)r * 256 + part * 8;
            float4 f0 = *(const float4*)src, f1 = *(const float4*)(src + 4);
            int d0 = part * 8;
            vtbl[(d0 + 0) * 136 + r] = f2bf(f0.x);
            vtbl[(d0 + 1) * 136 + r] = f2bf(f0.y);
            vtbl[(d0 + 2) * 136 + r] = f2bf(f0.z);
            vtbl[(d0 + 3) * 136 + r] = f2bf(f0.w);
            vtbl[(d0 + 4) * 136 + r] = f2bf(f1.x);
            vtbl[(d0 + 5) * 136 + r] = f2bf(f1.y);
            vtbl[(d0 + 6) * 136 + r] = f2bf(f1.z);
            vtbl[(d0 + 7) * 136 + r] = f2bf(f1.w);
        }
        int span = 128 - R;
        for (int e = tid; e < 32 * span; e += 256) {
            int d = e / span, rr = e - d * span;
            vtbl[d * 136 + R + rr] = 0;
        }
    };
    auto stageVt = [&]() {
        int j = tid >> 2, d0 = (tid & 3) * 8;
        uint4 pk = *(const uint4*)(vb + base + tid * 8);
        const ushort* u = (const ushort*)&pk;
#pragma unroll
        for (int ii = 0; ii < 8; ++ii) v_t[(d0 + ii) * 72 + j] = u[ii];
    };

    // ---- seg 1 ----
    {
        int row = tid >> 2, part = tid & 3;
        *(uint4*)&q_s[row * 40 + part * 8] = *(const uint4*)(qb + base + tid * 8);
        *(uint4*)&k_s[row * 40 + part * 8] = *(const uint4*)(kb + base + tid * 8);
    }
    if (tid < 64) {
        const float* cp = nco + (size_t)(n * 64 + tid) * 6;
        cwf[tid * 6 + 0] = cp[0] * 4.f; cwf[tid * 6 + 1] = cp[1] * 4.f;
        cwf[tid * 6 + 2] = cp[2] * 4.f; cwf[tid * 6 + 3] = cp[3] * 8.f;
        cwf[tid * 6 + 4] = cp[4] * 8.f; cwf[tid * 6 + 5] = cp[5] * 8.f;
    }
    stageD(dkg);
    __syncthreads();

    float lg[4][4];

    auto gatherX = [&](bool useJ) {
#pragma unroll
        for (int tt = 0; tt < 4; ++tt) {
            int j = tt * 16 + l4;
            float cj0 = cwf[j * 6 + 0], cj1 = cwf[j * 6 + 1], cj2 = cwf[j * 6 + 2];
#pragma unroll
            for (int reg = 0; reg < 4; ++reg) {
                int i = w * 16 + quad * 4 + reg;
                int x0 = min(max((int)floorf(cwf[i * 6 + 0] - cj0) + 20, 0), 39);
                int x1 = min(max((int)floorf(cwf[i * 6 + 1] - cj1) + 20, 0), 39);
                int x2 = min(max((int)floorf(cwf[i * 6 + 2] - cj2) + 20, 0), 39);
                int b = (useJ ? j : i) * 232;
                lg[tt][reg] += bf2f(dkq[b + x0]) + bf2f(dkq[b + 40 + x1])
                             + bf2f(dkq[b + 80 + x2]);
            }
        }
    };
    auto gatherR = [&](bool useJ) {
#pragma unroll
        for (int tt = 0; tt < 4; ++tt) {
            int j = tt * 16 + l4;
            float cj3 = cwf[j * 6 + 3], cj4 = cwf[j * 6 + 4], cj5 = cwf[j * 6 + 5];
#pragma unroll
            for (int reg = 0; reg < 4; ++reg) {
                int i = w * 16 + quad * 4 + reg;
                int r0 = min(max((int)floorf(cwf[i * 6 + 3] - cj3) + 16, 0), 31);
                int r1 = min(max((int)floorf(cwf[i * 6 + 4] - cj4) + 16, 0), 31);
                int r2 = min(max((int)floorf(cwf[i * 6 + 5] - cj5) + 16, 0), 31);
                int b = (useJ ? j : i) * 232;
                lg[tt][reg] += bf2f(dkq[b + 128 + r0]) + bf2f(dkq[b + 160 + r1])
                             + bf2f(dkq[b + 192 + r2]);
            }
        }
    };
    auto scatterX = [&]() {
#pragma unroll
        for (int tt = 0; tt < 4; ++tt) {
            int j = tt * 16 + l4;
            float cj0 = cwf[j * 6 + 0], cj1 = cwf[j * 6 + 1], cj2 = cwf[j * 6 + 2];
#pragma unroll
            for (int reg = 0; reg < 4; ++reg) {
                int i = w * 16 + quad * 4 + reg;
                int x0 = min(max((int)floorf(cwf[i * 6 + 0] - cj0) + 20, 0), 39);
                int x1 = min(max((int)floorf(cwf[i * 6 + 1] - cj1) + 20, 0), 39);
                int x2 = min(max((int)floorf(cwf[i * 6 + 2] - cj2) + 20, 0), 39);
                float* bi = &bins[i * 122];
                float a = lg[tt][reg];
                atomicAdd(bi + x0, a);
                atomicAdd(bi + 40 + x1, a);
                atomicAdd(bi + 80 + x2, a);
            }
        }
    };
    auto scatterR = [&]() {
#pragma unroll
        for (int tt = 0; tt < 4; ++tt) {
            int j = tt * 16 + l4;
            float cj3 = cwf[j * 6 + 3], cj4 = cwf[j * 6 + 4], cj5 = cwf[j * 6 + 5];
#pragma unroll
            for (int reg = 0; reg < 4; ++reg) {
                int i = w * 16 + quad * 4 + reg;
                int r0 = min(max((int)floorf(cwf[i * 6 + 3] - cj3) + 16, 0), 31);
                int r1 = min(max((int)floorf(cwf[i * 6 + 4] - cj4) + 16, 0), 31);
                int r2 = min(max((int)floorf(cwf[i * 6 + 5] - cj5) + 16, 0), 31);
                float* bi = &bins[i * 122];
                float a = lg[tt][reg];
                atomicAdd(bi + r0, a);
                atomicAdd(bi + 32 + r1, a);
                atomicAdd(bi + 64 + r2, a);
            }
        }
    };
    auto zeroBins = [&]() {
        float4 z = {0.f, 0.f, 0.f, 0.f};
        for (int e = tid * 4; e < 64 * 122; e += 1024) *(float4*)&bins[e] = z;
    };

    // ---- seg 2: QK + k-side gathers ----
    {
        short8 aq = *(const short8*)&q_s[(w * 16 + l4) * 40 + quad * 8];
#pragma unroll
        for (int tt = 0; tt < 4; ++tt) {
            short8 bk = *(const short8*)&k_s[(tt * 16 + l4) * 40 + quad * 8];
            f32x4 r = {0.f, 0.f, 0.f, 0.f};
            r = __builtin_amdgcn_mfma_f32_16x16x32_bf16(aq, bk, r, 0, 0, 0);
            lg[tt][0] = r[0]; lg[tt][1] = r[1]; lg[tt][2] = r[2]; lg[tt][3] = r[3];
        }
    }
    gatherX(true);
    gatherR(true);
    __syncthreads();

    // ---- seg 3: stage dq, v_t, vtbl_x ----
    stageD(dqg);
    stageVt();
    stageVtbl(vxt + h * 32, 120);
    __syncthreads();

    // ---- seg 4: q-side gathers, softmax, attn write, AV ----
    gatherX(false);
    gatherR(false);
#pragma unroll
    for (int reg = 0; reg < 4; ++reg) {
        float m = fmaxf(fmaxf(lg[0][reg], lg[1][reg]), fmaxf(lg[2][reg], lg[3][reg]));
        m = fmaxf(m, __shfl_xor(m, 1));
        m = fmaxf(m, __shfl_xor(m, 2));
        m = fmaxf(m, __shfl_xor(m, 4));
        m = fmaxf(m, __shfl_xor(m, 8));
        float s = 0.f;
#pragma unroll
        for (int tt = 0; tt < 4; ++tt) { lg[tt][reg] = __expf(lg[tt][reg] - m); s += lg[tt][reg]; }
        s += __shfl_xor(s, 1); s += __shfl_xor(s, 2);
        s += __shfl_xor(s, 4); s += __shfl_xor(s, 8);
        float inv = 1.f / s;
#pragma unroll
        for (int tt = 0; tt < 4; ++tt) lg[tt][reg] *= inv;
    }
#pragma unroll
    for (int tt = 0; tt < 4; ++tt)
#pragma unroll
        for (int reg = 0; reg < 4; ++reg)
            attn_s[(w * 16 + quad * 4 + reg) * 72 + tt * 16 + l4] = f2bf(lg[tt][reg]);

    f32x4 acc0 = {0.f, 0.f, 0.f, 0.f}, acc1 = {0.f, 0.f, 0.f, 0.f};
#pragma unroll
    for (int s = 0; s < 2; ++s) {
        short8 af = *(const short8*)&attn_s[(w * 16 + l4) * 72 + s * 32 + quad * 8];
        short8 b0 = *(const short8*)&v_t[l4 * 72 + s * 32 + quad * 8];
        short8 b1 = *(const short8*)&v_t[(16 + l4) * 72 + s * 32 + quad * 8];
        acc0 = __builtin_amdgcn_mfma_f32_16x16x32_bf16(af, b0, acc0, 0, 0, 0);
        acc1 = __builtin_amdgcn_mfma_f32_16x16x32_bf16(af, b1, acc1, 0, 0, 0);
    }
    __syncthreads();

    // ---- seg 5..10: bins phases ----
    zeroBins();
    __syncthreads();
    scatterX();
    __syncthreads();

    auto atgemm = [&](int Rlim) {
#pragma unroll
        for (int s = 0; s < 4; ++s) {
            int koff = s * 32 + quad * 8;
            short8 af = {0, 0, 0, 0, 0, 0, 0, 0};
            if (koff < Rlim) {
                const float* ap = &bins[(w * 16 + l4) * 122 + koff];
#pragma unroll
                for (int ii = 0; ii < 8; ++ii) af[ii] = (short)f2bf(ap[ii]);
            }
            short8 b0 = *(const short8*)&vtbl[l4 * 136 + koff];
            short8 b1 = *(const short8*)&vtbl[(16 + l4) * 136 + koff];
            acc0 = __builtin_amdgcn_mfma_f32_16x16x32_bf16(af, b0, acc0, 0, 0, 0);
            acc1 = __builtin_amdgcn_mfma_f32_16x16x32_bf16(af, b1, acc1, 0, 0, 0);
        }
    };
    atgemm(120);
    __syncthreads();
    zeroBins();
    stageVtbl(vrt + h * 32, 96);
    __syncthreads();
    scatterR();
    __syncthreads();
    atgemm(96);

    {
        ushort* op = aout + (size_t)(n * 64 + w * 16 + quad * 4) * 256 + h * 32;
#pragma unroll
        for (int reg = 0; reg < 4; ++reg) {
            op[reg * 256 + l4] = f2bf(acc0[reg]);
            op[reg * 256 + 16 + l4] = f2bf(acc1[reg]);
        }
    }
}

// ---------------------------------------------------------------------------
// Fallback: round-10 monolithic k_attn (167 µs proven) if ws too small.
// ---------------------------------------------------------------------------
#define DBS 122
__global__ __launch_bounds__(256, 2) void k_attn_mono(
    const ushort* __restrict__ qb, const ushort* __restrict__ kb, const ushort* __restrict__ vb,
    const float* __restrict__ nco,
    const float* __restrict__ qxt, const float* __restrict__ kxt, const float* __restrict__ vxt,
    const float* __restrict__ qrt, const float* __restrict__ krt, const float* __restrict__ vrt,
    ushort* __restrict__ aout)
{
    __shared__ __align__(16) float dbuf[64 * DBS];
    __shared__ __align__(16) ushort U[11264];
    __shared__ __align__(16) float cwf[64 * 6];
    ushort* q_s  = U;
    ushort* k_s  = U + 2560;
    ushort* tbl  = U + 5120;
    ushort* attn_s = U;
    ushort* v_t    = U + 4608;
    ushort* vtbl   = U + 6912;

    const int tid = threadIdx.x;
    const int n = blockIdx.x >> 3;
    const int h = blockIdx.x & 7;
    const int w = tid >> 6;
    const int l4 = tid & 15;
    const int quad = (tid >> 4) & 3;
    const size_t base = (size_t)((n * 8 + h) * 64) * 32;

    {
        int row = tid >> 2, part = tid & 3;
        *(uint4*)&q_s[row * 40 + part * 8] = *(const uint4*)(qb + base + tid * 8);
        *(uint4*)&k_s[row * 40 + part * 8] = *(const uint4*)(kb + base + tid * 8);
    }
    if (tid < 64) {
        const float* cp = nco + (size_t)(n * 64 + tid) * 6;
        cwf[tid * 6 + 0] = cp[0] * 4.f; cwf[tid * 6 + 1] = cp[1] * 4.f;
        cwf[tid * 6 + 2] = cp[2] * 4.f; cwf[tid * 6 + 3] = cp[3] * 8.f;
        cwf[tid * 6 + 4] = cp[4] * 8.f; cwf[tid * 6 + 5] = cp[5] * 8.f;
    }
    auto stageTbl = [&](const float* tbg, int R, int Rpad) {
        for (int e = tid; e < R * 4; e += 256) {
            int r = e >> 2, part = e & 3;
            const float* src = tbg + (size_t)r * 256 + part * 8;
            float4 f0 = *(const float4*)src, f1 = *(const float4*)(src + 4);
            union { ushort u[8]; uint4 v; } pk;
            pk.u[0] = f2bf(f0.x); pk.u[1] = f2bf(f0.y); pk.u[2] = f2bf(f0.z); pk.u[3] = f2bf(f0.w);
            pk.u[4] = f2bf(f1.x); pk.u[5] = f2bf(f1.y); pk.u[6] = f2bf(f1.z); pk.u[7] = f2bf(f1.w);
            *(uint4*)&tbl[r * 40 + part * 8] = pk.v;
        }
        for (int e = tid; e < (Rpad - R) * 40; e += 256) tbl[R * 40 + e] = 0;
    };
    auto stageVtbl = [&](const float* tbg, int R) {
        for (int e = tid; e < R * 4; e += 256) {
            int r = e >> 2, part = e & 3;
            const float* src = tbg + (size_t)r * 256 + part * 8;
            float4 f0 = *(const float4*)src, f1 = *(const float4*)(src + 4);
            int d0 = part * 8;
            vtbl[(d0 + 0) * 136 + r] = f2bf(f0.x);
            vtbl[(d0 + 1) * 136 + r] = f2bf(f0.y);
            vtbl[(d0 + 2) * 136 + r] = f2bf(f0.z);
            vtbl[(d0 + 3) * 136 + r] = f2bf(f0.w);
            vtbl[(d0 + 4) * 136 + r] = f2bf(f1.x);
            vtbl[(d0 + 5) * 136 + r] = f2bf(f1.y);
            vtbl[(d0 + 6) * 136 + r] = f2bf(f1.z);
            vtbl[(d0 + 7) * 136 + r] = f2bf(f1.w);
        }
        int span = 128 - R;
        for (int e = tid; e < 32 * span; e += 256) {
            int d = e / span, rr = e - d * span;
            vtbl[d * 136 + R + rr] = 0;
        }
    };
    auto stageVt = [&]() {
        int j = tid >> 2, d0 = (tid & 3) * 8;
        uint4 pk = *(const uint4*)(vb + base + tid * 8);
        const ushort* u = (const ushort*)&pk;
#pragma unroll
        for (int ii = 0; ii < 8; ++ii) v_t[(d0 + ii) * 72 + j] = u[ii];
    };
    auto tgemm = [&](const ushort* a_s, int NT, int maxc) {
        short8 af = *(const short8*)&a_s[(w * 16 + l4) * 40 + quad * 8];
        for (int tt = 0; tt < NT; ++tt) {
            short8 bf = *(const short8*)&tbl[(tt * 16 + l4) * 40 + quad * 8];
            f32x4 a = {0.f, 0.f, 0.f, 0.f};
            a = __builtin_amdgcn_mfma_f32_16x16x32_bf16(af, bf, a, 0, 0, 0);
            int col = tt * 16 + l4;
            int rb = w * 16 + quad * 4;
            if (col < maxc) {
                dbuf[(rb + 0) * DBS + col] = a[0];
                dbuf[(rb + 1) * DBS + col] = a[1];
                dbuf[(rb + 2) * DBS + col] = a[2];
                dbuf[(rb + 3) * DBS + col] = a[3];
            }
        }
    };
    stageTbl(kxt + h * 32, 120, 128);
    __syncthreads();
    float lg[4][4];
    auto gatherX = [&](bool useJ) {
#pragma unroll
        for (int tt = 0; tt < 4; ++tt) {
            int j = tt * 16 + l4;
            float cj0 = cwf[j * 6 + 0], cj1 = cwf[j * 6 + 1], cj2 = cwf[j * 6 + 2];
#pragma unroll
            for (int reg = 0; reg < 4; ++reg) {
                int i = w * 16 + quad * 4 + reg;
                int x0 = min(max((int)floorf(cwf[i * 6 + 0] - cj0) + 20, 0), 39);
                int x1 = min(max((int)floorf(cwf[i * 6 + 1] - cj1) + 20, 0), 39);
                int x2 = min(max((int)floorf(cwf[i * 6 + 2] - cj2) + 20, 0), 39);
                int b = (useJ ? j : i) * DBS;
                lg[tt][reg] += dbuf[b + x0] + dbuf[b + 40 + x1] + dbuf[b + 80 + x2];
            }
        }
    };
    auto gatherRm = [&](bool useJ) {
#pragma unroll
        for (int tt = 0; tt < 4; ++tt) {
            int j = tt * 16 + l4;
            float cj3 = cwf[j * 6 + 3], cj4 = cwf[j * 6 + 4], cj5 = cwf[j * 6 + 5];
#pragma unroll
            for (int reg = 0; reg < 4; ++reg) {
                int i = w * 16 + quad * 4 + reg;
                int r0 = min(max((int)floorf(cwf[i * 6 + 3] - cj3) + 16, 0), 31);
                int r1 = min(max((int)floorf(cwf[i * 6 + 4] - cj4) + 16, 0), 31);
                int r2 = min(max((int)floorf(cwf[i * 6 + 5] - cj5) + 16, 0), 31);
                int b = (useJ ? j : i) * DBS;
                lg[tt][reg] += dbuf[b + r0] + dbuf[b + 32 + r1] + dbuf[b + 64 + r2];
            }
        }
    };
    auto scatterX = [&]() {
#pragma unroll
        for (int tt = 0; tt < 4; ++tt) {
            int j = tt * 16 + l4;
            float cj0 = cwf[j * 6 + 0], cj1 = cwf[j * 6 + 1], cj2 = cwf[j * 6 + 2];
#pragma unroll
            for (int reg = 0; reg < 4; ++reg) {
                int i = w * 16 + quad * 4 + reg;
                int x0 = min(max((int)floorf(cwf[i * 6 + 0] - cj0) + 20, 0), 39);
                int x1 = min(max((int)floorf(cwf[i * 6 + 1] - cj1) + 20, 0), 39);
                int x2 = min(max((int)floorf(cwf[i * 6 + 2] - cj2) + 20, 0), 39);
                float* bi = &dbuf[i * DBS];
                float a = lg[tt][reg];
                atomicAdd(bi + x0, a);
                atomicAdd(bi + 40 + x1, a);
                atomicAdd(bi + 80 + x2, a);
            }
        }
    };
    auto scatterRm = [&]() {
#pragma unroll
        for (int tt = 0; tt < 4; ++tt) {
            int j = tt * 16 + l4;
            float cj3 = cwf[j * 6 + 3], cj4 = cwf[j * 6 + 4], cj5 = cwf[j * 6 + 5];
#pragma unroll
            for (int reg = 0; reg < 4; ++reg) {
                int i = w * 16 + quad * 4 + reg;
                int r0 = min(max((int)floorf(cwf[i * 6 + 3] - cj3) + 16, 0), 31);
                int r1 = min(max((int)floorf(cwf[i * 6 + 4] - cj4) + 16, 0), 31);
                int r2 = min(max((int)floorf(cwf[i * 6 + 5] - cj5) + 16, 0), 31);
                float* bi = &dbuf[i * DBS];
                float a = lg[tt][reg];
                atomicAdd(bi + r0, a);
                atomicAdd(bi + 32 + r1, a);
                atomicAdd(bi + 64 + r2, a);
            }
        }
    };
    auto zeroBins = [&]() {
        float4 z = {0.f, 0.f, 0.f, 0.f};
        for (int e = tid * 4; e < 64 * DBS; e += 1024) *(float4*)&dbuf[e] = z;
    };
    {
        short8 aq = *(const short8*)&q_s[(w * 16 + l4) * 40 + quad * 8];
#pragma unroll
        for (int tt = 0; tt < 4; ++tt) {
            short8 bk = *(const short8*)&k_s[(tt * 16 + l4) * 40 + quad * 8];
            f32x4 r = {0.f, 0.f, 0.f, 0.f};
            r = __builtin_amdgcn_mfma_f32_16x16x32_bf16(aq, bk, r, 0, 0, 0);
            lg[tt][0] = r[0]; lg[tt][1] = r[1]; lg[tt][2] = r[2]; lg[tt][3] = r[3];
        }
    }
    tgemm(k_s, 8, 120);
    __syncthreads();
    gatherX(true);
    stageTbl(krt + h * 32, 96, 96);
    __syncthreads();
    tgemm(k_s, 6, 96);
    __syncthreads();
    gatherRm(true);
    stageTbl(qxt + h * 32, 120, 128);
    __syncthreads();
    tgemm(q_s, 8, 120);
    __syncthreads();
    gatherX(false);
    stageTbl(qrt + h * 32, 96, 96);
    __syncthreads();
    tgemm(q_s, 6, 96);
    __syncthreads();
    gatherRm(false);
    stageVtbl(vxt + h * 32, 120);
    stageVt();
    __syncthreads();
#pragma unroll
    for (int reg = 0; reg < 4; ++reg) {
        float m = fmaxf(fmaxf(lg[0][reg], lg[1][reg]), fmaxf(lg[2][reg], lg[3][reg]));
        m = fmaxf(m, __shfl_xor(m, 1));
        m = fmaxf(m, __shfl_xor(m, 2));
        m = fmaxf(m, __shfl_xor(m, 4));
        m = fmaxf(m, __shfl_xor(m, 8));
        float s = 0.f;
#pragma unroll
        for (int tt = 0; tt < 4; ++tt) { lg[tt][reg] = __expf(lg[tt][reg] - m); s += lg[tt][reg]; }
        s += __shfl_xor(s, 1); s += __shfl_xor(s, 2);
        s += __shfl_xor(s, 4); s += __shfl_xor(s, 8);
        float inv = 1.f / s;
#pragma unroll
        for (int tt = 0; tt < 4; ++tt) lg[tt][reg] *= inv;
    }
#pragma unroll
    for (int tt = 0; tt < 4; ++tt)
#pragma unroll
        for (int reg = 0; reg < 4; ++reg)
            attn_s[(w * 16 + quad * 4 + reg) * 72 + tt * 16 + l4] = f2bf(lg[tt][reg]);
    zeroBins();
    __syncthreads();
    scatterX();
    f32x4 acc0 = {0.f, 0.f, 0.f, 0.f}, acc1 = {0.f, 0.f, 0.f, 0.f};
#pragma unroll
    for (int s = 0; s < 2; ++s) {
        short8 af = *(const short8*)&attn_s[(w * 16 + l4) * 72 + s * 32 + quad * 8];
        short8 b0 = *(const short8*)&v_t[l4 * 72 + s * 32 + quad * 8];
        short8 b1 = *(const short8*)&v_t[(16 + l4) * 72 + s * 32 + quad * 8];
        acc0 = __builtin_amdgcn_mfma_f32_16x16x32_bf16(af, b0, acc0, 0, 0, 0);
        acc1 = __builtin_amdgcn_mfma_f32_16x16x32_bf16(af, b1, acc1, 0, 0, 0);
    }
    __syncthreads();
    auto atgemm = [&](int Rlim) {
#pragma unroll
        for (int s = 0; s < 4; ++s) {
            int koff = s * 32 + quad * 8;
            short8 af = {0, 0, 0, 0, 0, 0, 0, 0};
            if (koff < Rlim) {
                const float* ap = &dbuf[(w * 16 + l4) * DBS + koff];
#pragma unroll
                for (int ii = 0; ii < 8; ++ii) af[ii] = (short)f2bf(ap[ii]);
            }
            short8 b0 = *(const short8*)&vtbl[l4 * 136 + koff];
            short8 b1 = *(const short8*)&vtbl[(16 + l4) * 136 + koff];
            acc0 = __builtin_amdgcn_mfma_f32_16x16x32_bf16(af, b0, acc0, 0, 0, 0);
            acc1 = __builtin_amdgcn_mfma_f32_16x16x32_bf16(af, b1, acc1, 0, 0, 0);
        }
    };
    atgemm(120);
    __syncthreads();
    zeroBins();
    stageVtbl(vrt + h * 32, 96);
    __syncthreads();
    scatterRm();
    __syncthreads();
    atgemm(96);
    {
        ushort* op = aout + (size_t)(n * 64 + w * 16 + quad * 4) * 256 + h * 32;
#pragma unroll
        for (int reg = 0; reg < 4; ++reg) {
            op[reg * 256 + l4] = f2bf(acc0[reg]);
            op[reg * 256 + 16 + l4] = f2bf(acc1[reg]);
        }
    }
}

// ---------------------------------------------------------------------------
// Proj GEMM (bf16 MFMA): out = ao(bf16) @ proj_w(fp32, cast inline)^T + pb
// ---------------------------------------------------------------------------
__global__ __launch_bounds__(256) void k_proj(
    const ushort* __restrict__ A, const float* __restrict__ B,
    const float* __restrict__ bias, float* __restrict__ out)
{
    __shared__ __align__(16) ushort a_s[128 * 72];
    __shared__ __align__(16) ushort b_s[64 * 72];
    const int tid = threadIdx.x;
    const int m0 = blockIdx.y * 128;
    const int n0 = blockIdx.x * 64;
    const int w = tid >> 6, wm = w >> 1, wn = w & 1;
    const int l4 = tid & 15, quad = (tid >> 4) & 3;
    f32x4 acc[4][2];
#pragma unroll
    for (int mt = 0; mt < 4; ++mt)
#pragma unroll
        for (int nt = 0; nt < 2; ++nt) acc[mt][nt] = (f32x4){0.f, 0.f, 0.f, 0.f};

    for (int k0 = 0; k0 < 256; k0 += 64) {
#pragma unroll
        for (int l = 0; l < 4; ++l) {
            int e = tid + l * 256;
            int row = e >> 3, kq = e & 7;
            *(uint4*)&a_s[row * 72 + kq * 8] =
                *(const uint4*)(A + (size_t)(m0 + row) * 256 + k0 + kq * 8);
        }
#pragma unroll
        for (int l = 0; l < 2; ++l) {
            int e = tid + l * 256;
            int row = e >> 3, kq = e & 7;
            const float* bp = B + (size_t)(n0 + row) * 256 + k0 + kq * 8;
            float4 v0 = *(const float4*)bp, v1 = *(const float4*)(bp + 4);
            union { ushort u[8]; uint4 v; } pk;
            pk.u[0] = f2bf(v0.x); pk.u[1] = f2bf(v0.y); pk.u[2] = f2bf(v0.z); pk.u[3] = f2bf(v0.w);
            pk.u[4] = f2bf(v1.x); pk.u[5] = f2bf(v1.y); pk.u[6] = f2bf(v1.z); pk.u[7] = f2bf(v1.w);
            *(uint4*)&b_s[row * 72 + kq * 8] = pk.v;
        }
        __syncthreads();
#pragma unroll
        for (int kh = 0; kh < 2; ++kh) {
            short8 bf0 = *(const short8*)&b_s[(wn * 32 + l4) * 72 + kh * 32 + quad * 8];
            short8 bf1 = *(const short8*)&b_s[(wn * 32 + 16 + l4) * 72 + kh * 32 + quad * 8];
#pragma unroll
            for (int mt = 0; mt < 4; ++mt) {
                short8 af = *(const short8*)&a_s[(wm * 64 + mt * 16 + l4) * 72 + kh * 32 + quad * 8];
                acc[mt][0] = __builtin_amdgcn_mfma_f32_16x16x32_bf16(af, bf0, acc[mt][0], 0, 0, 0);
                acc[mt][1] = __builtin_amdgcn_mfma_f32_16x16x32_bf16(af, bf1, acc[mt][1], 0, 0, 0);
            }
        }
        __syncthreads();
    }
#pragma unroll
    for (int nt = 0; nt < 2; ++nt) {
        int c = n0 + wn * 32 + nt * 16 + l4;
        float bv = bias[c];
#pragma unroll
        for (int mt = 0; mt < 4; ++mt) {
            int mbase = m0 + wm * 64 + mt * 16 + quad * 4;
#pragma unroll
            for (int reg = 0; reg < 4; ++reg)
                out[(size_t)(mbase + reg) * 256 + c] = acc[mt][nt][reg] + bv;
        }
    }
}

extern "C" void kernel_launch(void* const* d_in, const int* in_sizes, int n_in,
                              void* d_out, int out_size, void* d_ws, size_t ws_size,
                              hipStream_t stream)
{
    const float* feats = (const float*)d_in[0];
    const float* nco   = (const float*)d_in[1];
    const float* qkvw  = (const float*)d_in[2];
    const float* qkvb  = (const float*)d_in[3];
    const float* qxt   = (const float*)d_in[4];
    const float* kxt   = (const float*)d_in[5];
    const float* vxt   = (const float*)d_in[6];
    const float* qrt   = (const float*)d_in[7];
    const float* krt   = (const float*)d_in[8];
    const float* vrt   = (const float*)d_in[9];
    const float* pw    = (const float*)d_in[10];
    const float* pb    = (const float*)d_in[11];
    float* out = (float*)d_out;

    ushort* qb  = (ushort*)d_ws;                       // [128][8][64][32] bf16
    ushort* kb  = qb + (size_t)2097152;
    ushort* vb  = kb + (size_t)2097152;
    ushort* aob = vb + (size_t)2097152;                // [8192][256] bf16
    ushort* dkg = aob + (size_t)2097152;               // [1024][64][224] bf16
    ushort* dqg = dkg + (size_t)14680064;              // end: 37,748,736 el

    k_qkv<<<dim3(12, 64), 256, 0, stream>>>(feats, qkvw, qkvb, qb, kb, vb);
    if (ws_size >= (size_t)75497472) {
        k_dt<<<dim3(1024), 256, 0, stream>>>(qb, kb, qxt, kxt, qrt, krt, dkg, dqg);
        k_attn_split<<<dim3(1024), 256, 0, stream>>>(qb, kb, vb, nco, dkg, dqg, vxt, vrt, aob);
    } else {
        k_attn_mono<<<dim3(1024), 256, 0, stream>>>(qb, kb, vb, nco, qxt, kxt, vxt, qrt, krt, vrt, aob);
    }
    k_proj<<<dim3(4, 64), 256, 0, stream>>>(aob, pw, pb, out);
}